// Round 16
// baseline (127.106 us; speedup 1.0000x reference)
//
#include <hip/hip_runtime.h>

#define N_NODES 50000
#define C_CH 64
#define M_TERMS 3      // ||-t*L||inf <= ~0.52 worst row; tail after 3 terms ~0.017 abs
#define BKT_SHIFT 8
#define BKT_ROWS 256   // rows per bucket
#define CSR_CAP 6912   // padded csr slice per bucket (mean 4096+pad, +40 sigma)
#define SEG 2048       // edges per binA block segment

typedef unsigned short ushort_t;
typedef unsigned int uint_t;

__device__ __forceinline__ float bf2f(uint_t h16) {  // low 16 bits = bf16
    return __uint_as_float(h16 << 16);
}
__device__ __forceinline__ ushort_t f2bf(float f) {  // round-to-nearest-even
    uint_t u = __float_as_uint(f);
    u += 0x7FFFu + ((u >> 16) & 1u);
    return (ushort_t)(u >> 16);
}

// broadcast csr entry j to all lanes of each 8-lane group:
// BitMode target = (lane & 0x18) | j  -> offset = (j << 5) | 0x18
#define BCAST(M, J) ((uint_t)__builtin_amdgcn_ds_swizzle((int)(M), (((J) << 5) | 0x18)))

// ---------------- CSR build ----------------

// x (fp32) -> bf16x8 (uint4); 8 elems/thread
__global__ void cvt_kernel(const float4* __restrict__ x, uint4* __restrict__ xb, int n8) {
    int i = blockIdx.x * blockDim.x + threadIdx.x;
    if (i < n8) {
        float4 a = x[2 * i], b = x[2 * i + 1];
        xb[i] = make_uint4((uint_t)f2bf(a.x) | ((uint_t)f2bf(a.y) << 16),
                           (uint_t)f2bf(a.z) | ((uint_t)f2bf(a.w) << 16),
                           (uint_t)f2bf(b.x) | ((uint_t)f2bf(b.y) << 16),
                           (uint_t)f2bf(b.z) | ((uint_t)f2bf(b.w) << 16));
    }
}

// Phase A, BLOCK-MAJOR: each block sorts its 2048 edges by bucket into its own
// dense staging segment [blk*SEG, blk*SEG+2048) and records per-bucket runs in
// tab[blk*256+b] = base | (cnt<<16). All global writes dense & aligned.
__global__ __launch_bounds__(256) void
binA_kernel(const int* __restrict__ src, const int* __restrict__ dst,
            const float* __restrict__ w, uint_t* __restrict__ tab,
            uint2* __restrict__ staging, int E) {
    __shared__ int bcnt[256];
    __shared__ int bbase[256];
    __shared__ int wsum[4];
    const int tid = threadIdx.x;
    const int base = blockIdx.x * SEG;
    bcnt[tid] = 0;
    __syncthreads();
    int lpos[8], bkt[8], sr[8];
    uint_t pay[8];
    #pragma unroll
    for (int j = 0; j < 8; ++j) {
        int e = base + j * 256 + tid;
        if (e < E) {
            int s = src[e];
            int b = s >> BKT_SHIFT;
            sr[j] = s;
            bkt[j] = b;
            pay[j] = (uint_t)dst[e] | ((uint_t)f2bf(w[e]) << 16);
            lpos[j] = atomicAdd(&bcnt[b], 1);
        } else {
            bkt[j] = -1;
        }
    }
    __syncthreads();
    // exclusive scan of bcnt over 256 (4 waves)
    const int lane = tid & 63;
    const int wv = tid >> 6;
    int c = bcnt[tid];
    int s = c;
    #pragma unroll
    for (int off = 1; off < 64; off <<= 1) {
        int u = __shfl_up(s, off, 64);
        if (lane >= off) s += u;
    }
    if (lane == 63) wsum[wv] = s;
    __syncthreads();
    if (tid == 0) {
        int a = 0;
        #pragma unroll
        for (int j = 0; j < 4; ++j) { int t = wsum[j]; wsum[j] = a; a += t; }
    }
    __syncthreads();
    int myb = wsum[wv] + s - c;  // exclusive prefix within segment
    bbase[tid] = myb;
    tab[(size_t)blockIdx.x * 256 + tid] = (uint_t)myb | ((uint_t)c << 16);
    __syncthreads();
    #pragma unroll
    for (int j = 0; j < 8; ++j) {
        if (bkt[j] >= 0)
            staging[base + bbase[bkt[j]] + lpos[j]] = make_uint2((uint_t)sr[j], pay[j]);
    }
}

// Phase B: one 256-thread WG per bucket. Thread t walks blocks {t, t+256, ...},
// reading the bucket's run in each block segment (via tab). Pass 1: LDS
// histogram; LDS padded scan -> row bases; pass 2: scatter into the bucket's
// PRIVATE csr slice; emit per-row (beg,end), degree-sorted perm, zero pad slots.
__global__ __launch_bounds__(256) void
binB_kernel(const uint2* __restrict__ staging, const uint_t* __restrict__ tab,
            int nblk, int2* __restrict__ rp, int* __restrict__ perm,
            uint_t* __restrict__ csr, int n) {
    __shared__ int lcnt[256];
    __shared__ int lbeg[256];
    __shared__ int lcur[256];
    __shared__ int wsum[4];
    __shared__ int ccls[16];
    __shared__ int cbase2[16];
    const int tid = threadIdx.x;
    const int b = blockIdx.x;
    const int r0 = b << BKT_SHIFT;
    lcnt[tid] = 0;
    lcur[tid] = 0;
    if (tid < 16) ccls[tid] = 0;
    __syncthreads();
    // pass 1: histogram from per-block runs
    for (int i = tid; i < nblk; i += 256) {
        uint_t t = tab[(size_t)i * 256 + b];
        int bas = t & 0xFFFFu;
        int c = t >> 16;
        const uint2* p = staging + (size_t)i * SEG + bas;
        for (int j = 0; j < c; ++j)
            atomicAdd(&lcnt[(int)p[j].x - r0], 1);
    }
    __syncthreads();
    // padded inclusive scan over 256 counts (4 waves)
    const int lane = tid & 63;
    const int wv = tid >> 6;
    int padded = (lcnt[tid] + 7) & ~7;
    int s = padded;
    #pragma unroll
    for (int off = 1; off < 64; off <<= 1) {
        int u = __shfl_up(s, off, 64);
        if (lane >= off) s += u;
    }
    if (lane == 63) wsum[wv] = s;
    __syncthreads();
    if (tid == 0) {
        int a = 0;
        #pragma unroll
        for (int j = 0; j < 4; ++j) { int t = wsum[j]; wsum[j] = a; a += t; }
    }
    __syncthreads();
    int beg = wsum[wv] + s - padded;  // exclusive padded prefix
    lbeg[tid] = beg;
    // degree-class histogram -> perm (wave load balance in taylor)
    int r = r0 + tid;
    int cls = min(padded >> 4, 15);
    if (r < n) atomicAdd(&ccls[cls], 1);
    __syncthreads();
    if (tid == 0) {
        int a = 0;
        #pragma unroll
        for (int j = 0; j < 16; ++j) { int t = ccls[j]; cbase2[j] = a; a += t; }
    }
    __syncthreads();
    if (tid < 16) ccls[tid] = 0;
    __syncthreads();
    if (r < n) {
        int slot = cbase2[cls] + atomicAdd(&ccls[cls], 1);
        perm[r0 + slot] = r;
    }
    __syncthreads();
    // pass 2: scatter (runs L2-hot from pass 1)
    const int cbase = b * CSR_CAP;
    for (int i = tid; i < nblk; i += 256) {
        uint_t t = tab[(size_t)i * 256 + b];
        int bas = t & 0xFFFFu;
        int c = t >> 16;
        const uint2* p = staging + (size_t)i * SEG + bas;
        for (int j = 0; j < c; ++j) {
            uint2 e = p[j];
            int li = (int)e.x - r0;
            int pp = cbase + lbeg[li] + atomicAdd(&lcur[li], 1);
            csr[pp] = e.y;
        }
    }
    __syncthreads();
    if (r < n) {
        rp[r] = make_int2(cbase + beg, cbase + beg + padded);
        for (int p = cbase + beg + lcnt[tid]; p < cbase + beg + padded; ++p)
            csr[p] = 0;
    }
}

// ---- fallback path (small ws): global hist + scans + atomic scatter ----
__global__ void hist_kernel(const int* __restrict__ src, int* __restrict__ cnt, int E) {
    int e = blockIdx.x * blockDim.x + threadIdx.x;
    if (e < E) atomicAdd(&cnt[src[e]], 1);
}

__global__ void scan1_kernel(const int* __restrict__ cnt, int* __restrict__ row_ptr,
                             int* __restrict__ blk_sum, int n) {
    __shared__ int wsum[16];
    const int tid = threadIdx.x;
    const int lane = tid & 63;
    const int wv = tid >> 6;
    int i = blockIdx.x * 1024 + tid;
    int vr = (i < n) ? cnt[i] : 0;
    int v = (vr + 7) & ~7;
    int s = v;
    #pragma unroll
    for (int off = 1; off < 64; off <<= 1) {
        int u = __shfl_up(s, off, 64);
        if (lane >= off) s += u;
    }
    if (lane == 63) wsum[wv] = s;
    __syncthreads();
    if (wv == 0) {
        int ws = (lane < 16) ? wsum[lane] : 0;
        #pragma unroll
        for (int off = 1; off < 16; off <<= 1) {
            int u = __shfl_up(ws, off, 64);
            if (lane >= off) ws += u;
        }
        if (lane < 16) wsum[lane] = ws;
    }
    __syncthreads();
    int incl = s + ((wv == 0) ? 0 : wsum[wv - 1]);
    if (i < n) row_ptr[i + 1] = incl;
    if (tid == 1023) blk_sum[blockIdx.x] = incl;
}

__global__ void scan3_kernel(int* __restrict__ row_ptr, int* __restrict__ pos,
                             int2* __restrict__ rp, int* __restrict__ perm,
                             const int* __restrict__ blk_sum,
                             const int* __restrict__ cnt, int n, int nb) {
    __shared__ int soff[64];
    const int tid = threadIdx.x;
    if (tid < 64) {
        int v = (tid < nb) ? blk_sum[tid] : 0;
        int s = v;
        #pragma unroll
        for (int off = 1; off < 64; off <<= 1) {
            int u = __shfl_up(s, off, 64);
            if (tid >= off) s += u;
        }
        soff[tid] = s - v;
    }
    __syncthreads();
    int i = blockIdx.x * blockDim.x + tid;
    if (i < n) {
        int incl = row_ptr[i + 1] + soff[i >> 10];
        int padded = (cnt[i] + 7) & ~7;
        pos[i] = incl - padded;
        rp[i] = make_int2(incl - padded, incl);
        perm[i] = i;
    }
}

__global__ void scatter_kernel(const int* __restrict__ src, const int* __restrict__ dst,
                               const float* __restrict__ w, int* __restrict__ pos,
                               uint_t* __restrict__ csr, int E) {
    int e = blockIdx.x * blockDim.x + threadIdx.x;
    if (e < E) {
        int r = src[e];
        int p = atomicAdd(&pos[r], 1);
        csr[p] = (uint_t)dst[e] | ((uint_t)f2bf(w[e]) << 16);
    }
}

// ---------------- diffusion ----------------
// 8 lanes per row x uint4 (8 bf16 ch) = 128B row; 8 rows/wave via degree-sorted
// perm; 16-wide iteration; cooperative csr load (1/lane) + ds_swizzle broadcast.
// mode: 0 term only; 1 first+acc; 2 acc RMW; 3 FINAL.

__global__ __launch_bounds__(256) void
taylor_kernel(const int2* __restrict__ rp, const int* __restrict__ perm,
              const uint_t* __restrict__ csr,
              const uint4* __restrict__ term_in, uint4* __restrict__ term_out,
              float4* __restrict__ acc, const float4* __restrict__ x,
              const uint4* __restrict__ terms_all, size_t term_stride,
              const float* __restrict__ t_ptr,
              float inv_k, int n, int mode) {
    int gid = blockIdx.x * blockDim.x + threadIdx.x;
    int slot = gid >> 3;
    if (slot >= n) return;
    int row = perm[slot];
    int lane = gid & 7;
    float t = fmaxf(t_ptr[0], 1e-8f);
    float coef = -t * inv_k;
    int2 be = rp[row];
    int beg = be.x;
    int end = be.y;   // (end - beg) % 8 == 0

    float c0 = 0.f, c1 = 0.f, c2 = 0.f, c3 = 0.f;
    float c4 = 0.f, c5 = 0.f, c6 = 0.f, c7 = 0.f;
    for (int e = beg; e < end; e += 16) {
        int eB = e + 8;
        bool hasB = eB < end;
        uint_t mA = csr[e + lane];
        uint_t mB = csr[(hasB ? eB : e) + lane];   // re-read A when no B (wB=0)
        uint_t a0 = BCAST(mA, 0), a1 = BCAST(mA, 1), a2 = BCAST(mA, 2), a3 = BCAST(mA, 3);
        uint_t a4 = BCAST(mA, 4), a5 = BCAST(mA, 5), a6 = BCAST(mA, 6), a7 = BCAST(mA, 7);
        uint_t b0 = BCAST(mB, 0), b1 = BCAST(mB, 1), b2 = BCAST(mB, 2), b3 = BCAST(mB, 3);
        uint_t b4 = BCAST(mB, 4), b5 = BCAST(mB, 5), b6 = BCAST(mB, 6), b7 = BCAST(mB, 7);
        uint4 vA0 = term_in[(size_t)(a0 & 0xFFFFu) * 8 + lane];
        uint4 vA1 = term_in[(size_t)(a1 & 0xFFFFu) * 8 + lane];
        uint4 vA2 = term_in[(size_t)(a2 & 0xFFFFu) * 8 + lane];
        uint4 vA3 = term_in[(size_t)(a3 & 0xFFFFu) * 8 + lane];
        uint4 vA4 = term_in[(size_t)(a4 & 0xFFFFu) * 8 + lane];
        uint4 vA5 = term_in[(size_t)(a5 & 0xFFFFu) * 8 + lane];
        uint4 vA6 = term_in[(size_t)(a6 & 0xFFFFu) * 8 + lane];
        uint4 vA7 = term_in[(size_t)(a7 & 0xFFFFu) * 8 + lane];
        uint4 vB0 = term_in[(size_t)(b0 & 0xFFFFu) * 8 + lane];
        uint4 vB1 = term_in[(size_t)(b1 & 0xFFFFu) * 8 + lane];
        uint4 vB2 = term_in[(size_t)(b2 & 0xFFFFu) * 8 + lane];
        uint4 vB3 = term_in[(size_t)(b3 & 0xFFFFu) * 8 + lane];
        uint4 vB4 = term_in[(size_t)(b4 & 0xFFFFu) * 8 + lane];
        uint4 vB5 = term_in[(size_t)(b5 & 0xFFFFu) * 8 + lane];
        uint4 vB6 = term_in[(size_t)(b6 & 0xFFFFu) * 8 + lane];
        uint4 vB7 = term_in[(size_t)(b7 & 0xFFFFu) * 8 + lane];
        float fB = hasB ? 1.f : 0.f;
        #define FMA8(W, V)                              \
            c0 = fmaf(W, bf2f((V).x & 0xFFFFu), c0);    \
            c1 = fmaf(W, bf2f((V).x >> 16),     c1);    \
            c2 = fmaf(W, bf2f((V).y & 0xFFFFu), c2);    \
            c3 = fmaf(W, bf2f((V).y >> 16),     c3);    \
            c4 = fmaf(W, bf2f((V).z & 0xFFFFu), c4);    \
            c5 = fmaf(W, bf2f((V).z >> 16),     c5);    \
            c6 = fmaf(W, bf2f((V).w & 0xFFFFu), c6);    \
            c7 = fmaf(W, bf2f((V).w >> 16),     c7);
        FMA8(bf2f(a0 >> 16), vA0)
        FMA8(bf2f(a1 >> 16), vA1)
        FMA8(bf2f(a2 >> 16), vA2)
        FMA8(bf2f(a3 >> 16), vA3)
        FMA8(bf2f(a4 >> 16), vA4)
        FMA8(bf2f(a5 >> 16), vA5)
        FMA8(bf2f(a6 >> 16), vA6)
        FMA8(bf2f(a7 >> 16), vA7)
        FMA8(fB * bf2f(b0 >> 16), vB0)
        FMA8(fB * bf2f(b1 >> 16), vB1)
        FMA8(fB * bf2f(b2 >> 16), vB2)
        FMA8(fB * bf2f(b3 >> 16), vB3)
        FMA8(fB * bf2f(b4 >> 16), vB4)
        FMA8(fB * bf2f(b5 >> 16), vB5)
        FMA8(fB * bf2f(b6 >> 16), vB6)
        FMA8(fB * bf2f(b7 >> 16), vB7)
        #undef FMA8
    }
    c0 *= coef; c1 *= coef; c2 *= coef; c3 *= coef;
    c4 *= coef; c5 *= coef; c6 *= coef; c7 *= coef;
    size_t idx = (size_t)row * 8 + lane;
    if (mode != 3) {
        term_out[idx] = make_uint4((uint_t)f2bf(c0) | ((uint_t)f2bf(c1) << 16),
                                   (uint_t)f2bf(c2) | ((uint_t)f2bf(c3) << 16),
                                   (uint_t)f2bf(c4) | ((uint_t)f2bf(c5) << 16),
                                   (uint_t)f2bf(c6) | ((uint_t)f2bf(c7) << 16));
    }
    if (mode == 1) {
        size_t fi = (size_t)row * 16 + lane * 2;
        float4 xa = x[fi], xb4 = x[fi + 1];
        acc[fi]     = make_float4(xa.x + c0, xa.y + c1, xa.z + c2, xa.w + c3);
        acc[fi + 1] = make_float4(xb4.x + c4, xb4.y + c5, xb4.z + c6, xb4.w + c7);
    } else if (mode == 2) {
        size_t fi = (size_t)row * 16 + lane * 2;
        float4 aa = acc[fi], ab = acc[fi + 1];
        acc[fi]     = make_float4(aa.x + c0, aa.y + c1, aa.z + c2, aa.w + c3);
        acc[fi + 1] = make_float4(ab.x + c4, ab.y + c5, ab.z + c6, ab.w + c7);
    } else if (mode == 3) {
        float s0 = c0, s1 = c1, s2 = c2, s3 = c3;
        float s4 = c4, s5 = c5, s6 = c6, s7 = c7;
        #pragma unroll
        for (int j = 0; j < M_TERMS - 1; ++j) {
            uint4 tv = terms_all[(size_t)j * term_stride + idx];
            s0 += bf2f(tv.x & 0xFFFFu);
            s1 += bf2f(tv.x >> 16);
            s2 += bf2f(tv.y & 0xFFFFu);
            s3 += bf2f(tv.y >> 16);
            s4 += bf2f(tv.z & 0xFFFFu);
            s5 += bf2f(tv.z >> 16);
            s6 += bf2f(tv.w & 0xFFFFu);
            s7 += bf2f(tv.w >> 16);
        }
        size_t fi = (size_t)row * 16 + lane * 2;
        float4 xa = x[fi], xb4 = x[fi + 1];
        acc[fi]     = make_float4(xa.x + s0, xa.y + s1, xa.z + s2, xa.w + s3);
        acc[fi + 1] = make_float4(xb4.x + s4, xb4.y + s5, xb4.z + s6, xb4.w + s7);
    }
}

extern "C" void kernel_launch(void* const* d_in, const int* in_sizes, int n_in,
                              void* d_out, int out_size, void* d_ws, size_t ws_size,
                              hipStream_t stream) {
    const float* x    = (const float*)d_in[0];
    const int*   esrc = (const int*)d_in[1];
    const int*   edst = (const int*)d_in[2];
    const float* ew   = (const float*)d_in[3];
    const float* tp   = (const float*)d_in[4];
    float* out = (float*)d_out;

    const int E = in_sizes[1];
    const int N = N_NODES;
    const int NC = N * C_CH;
    const size_t TERM4 = (size_t)NC / 8;            // uint4 per term buffer
    const int nb = (N + BKT_ROWS - 1) / BKT_ROWS;   // 196 buckets
    const int nblk = (E + SEG - 1) / SEG;           // binA blocks / segments

    int* ws = (int*)d_ws;
    int2* rp     = (int2*)ws;                   // N pairs -> 100000, pad 100096
    int* perm    = ws + 100096;                 // N -> 150144
    int* cnt     = ws + 150144;                 // N (fallback) -> 200192
    int* row_ptr = ws + 200192;                 // N+1 (fallback) -> 250240
    int* pos     = ws + 250240;                 // N (fallback) -> 300288
    int* blk_sum = ws + 300288;                 // 64 -> 300352, pad 300416
    uint_t* tab  = (uint_t*)(ws + 300416);      // nblk*256 packed (base|cnt<<16)
    size_t csr_off = 300416 + (size_t)nblk * 256;
    uint_t* csr  = (uint_t*)(ws + csr_off);     // nb*CSR_CAP entries
    size_t stag_off = (csr_off + (size_t)nb * CSR_CAP + 1) & ~(size_t)1;
    uint2* staging = (uint2*)(ws + stag_off);   // nblk*SEG uint2 (block-major)
    size_t xb_off = (stag_off + 2 * (size_t)nblk * SEG + 3) & ~(size_t)3;
    uint4* xb = (uint4*)(ws + xb_off);          // TERM4 (16B aligned)

    const size_t needA = (xb_off + (size_t)M_TERMS * TERM4 * 4) * 4;
    const int pathA = (ws_size >= needA);

    cvt_kernel<<<(NC / 8 + 255) / 256, 256, 0, stream>>>((const float4*)x, xb, NC / 8);
    if (pathA) {
        binA_kernel<<<nblk, 256, 0, stream>>>(esrc, edst, ew, tab, staging, E);
        binB_kernel<<<nb, 256, 0, stream>>>(staging, tab, nblk, rp, perm, csr, N);
    } else {
        hipMemsetAsync(cnt, 0, (size_t)N * sizeof(int), stream);
        hist_kernel<<<(E + 255) / 256, 256, 0, stream>>>(esrc, cnt, E);
        const int nsb = (N + 1023) / 1024;
        scan1_kernel<<<nsb, 1024, 0, stream>>>(cnt, row_ptr, blk_sum, N);
        scan3_kernel<<<(N + 255) / 256, 256, 0, stream>>>(row_ptr, pos, rp, perm,
                                                          blk_sum, cnt, N, nsb);
        hipMemsetAsync(csr, 0, (size_t)nb * CSR_CAP * sizeof(uint_t), stream);
        scatter_kernel<<<(E + 255) / 256, 256, 0, stream>>>(esrc, edst, ew, pos, csr, E);
    }

    const int tgrid = (N * 8 + 255) / 256;   // 8 lanes per row

    if (pathA) {
        uint4* terms = xb + TERM4;  // M_TERMS-1 consecutive buffers
        taylor_kernel<<<tgrid, 256, 0, stream>>>(rp, perm, csr, xb, terms, nullptr,
                                                 nullptr, nullptr, 0, tp, 1.0f, N, 0);
        for (int k = 2; k <= M_TERMS - 1; ++k) {
            taylor_kernel<<<tgrid, 256, 0, stream>>>(rp, perm, csr,
                                                     terms + (size_t)(k - 2) * TERM4,
                                                     terms + (size_t)(k - 1) * TERM4,
                                                     nullptr, nullptr, nullptr, 0,
                                                     tp, 1.0f / (float)k, N, 0);
        }
        taylor_kernel<<<tgrid, 256, 0, stream>>>(rp, perm, csr,
                                                 terms + (size_t)(M_TERMS - 2) * TERM4,
                                                 terms, (float4*)out, (const float4*)x,
                                                 terms, TERM4,
                                                 tp, 1.0f / (float)M_TERMS, N, 3);
    } else {
        uint4* term_a = xb + TERM4;
        uint4* term_b = term_a + TERM4;
        taylor_kernel<<<tgrid, 256, 0, stream>>>(rp, perm, csr, xb, term_b,
                                                 (float4*)out, (const float4*)x,
                                                 nullptr, 0, tp, 1.0f, N, 1);
        const uint4* tin = term_b;
        uint4* tout = term_a;
        for (int k = 2; k <= M_TERMS; ++k) {
            taylor_kernel<<<tgrid, 256, 0, stream>>>(rp, perm, csr, tin, tout,
                                                     (float4*)out, (const float4*)x,
                                                     nullptr, 0, tp,
                                                     1.0f / (float)k, N, 2);
            const uint4* tmp = tin;
            tin = tout;
            tout = (uint4*)tmp;
        }
    }
}

// Round 17
// 100.503 us; speedup vs baseline: 1.2647x; 1.2647x over previous
//
#include <hip/hip_runtime.h>

#define N_NODES 50000
#define C_CH 64
#define M_TERMS 3      // ||-t*L||inf <= ~0.52 worst row; tail after 3 terms ~0.017 abs
#define BKT_SHIFT 8
#define BKT_ROWS 256   // rows per bucket
#define BKT_CAP 6400   // staging cap per bucket (mean ~5400 incl. line-pad, +13 sigma)
#define CSR_CAP 6912   // padded csr slice per bucket

typedef unsigned short ushort_t;
typedef unsigned int uint_t;

__device__ __forceinline__ float bf2f(uint_t h16) {  // low 16 bits = bf16
    return __uint_as_float(h16 << 16);
}
__device__ __forceinline__ ushort_t f2bf(float f) {  // round-to-nearest-even
    uint_t u = __float_as_uint(f);
    u += 0x7FFFu + ((u >> 16) & 1u);
    return (ushort_t)(u >> 16);
}

// broadcast csr entry j to all lanes of each 8-lane group:
// BitMode target = (lane & 0x18) | j  -> offset = (j << 5) | 0x18
#define BCAST(M, J) ((uint_t)__builtin_amdgcn_ds_swizzle((int)(M), (((J) << 5) | 0x18)))

// ---------------- CSR build ----------------

// x (fp32) -> bf16x8 (uint4); 8 elems/thread. Block 0 also inits bucket cursors.
__global__ void cvt_kernel(const float4* __restrict__ x, uint4* __restrict__ xb, int n8,
                           int* __restrict__ gcur) {
    int i = blockIdx.x * blockDim.x + threadIdx.x;
    if (blockIdx.x == 0 && threadIdx.x < 256) gcur[threadIdx.x] = threadIdx.x * BKT_CAP;
    if (i < n8) {
        float4 a = x[2 * i], b = x[2 * i + 1];
        xb[i] = make_uint4((uint_t)f2bf(a.x) | ((uint_t)f2bf(a.y) << 16),
                           (uint_t)f2bf(a.z) | ((uint_t)f2bf(a.w) << 16),
                           (uint_t)f2bf(b.x) | ((uint_t)f2bf(b.y) << 16),
                           (uint_t)f2bf(b.z) | ((uint_t)f2bf(b.w) << 16));
    }
}

// Phase A: bin edges by src>>8 into bucket-contiguous staging. Run allocations
// are rounded to 8 entries (64B lines) so no two blocks share a cache line;
// pad slots hold sentinels (src=0xFFFFFFFF) that binB skips.
__global__ __launch_bounds__(256) void
binA_kernel(const int* __restrict__ src, const int* __restrict__ dst,
            const float* __restrict__ w, int* __restrict__ gcur,
            uint2* __restrict__ staging, int E) {
    __shared__ int bcnt[256];
    __shared__ int bbase[256];
    const int tid = threadIdx.x;
    const int base = blockIdx.x * 2048;
    bcnt[tid] = 0;
    __syncthreads();
    int lpos[8], bkt[8], sr[8];
    uint_t pay[8];
    #pragma unroll
    for (int j = 0; j < 8; ++j) {
        int e = base + j * 256 + tid;
        if (e < E) {
            int s = src[e];
            int b = s >> BKT_SHIFT;
            sr[j] = s;
            bkt[j] = b;
            pay[j] = (uint_t)dst[e] | ((uint_t)f2bf(w[e]) << 16);
            lpos[j] = atomicAdd(&bcnt[b], 1);
        } else {
            bkt[j] = -1;
        }
    }
    __syncthreads();
    int c = bcnt[tid];
    if (c > 0) bbase[tid] = atomicAdd(&gcur[tid], (c + 7) & ~7);  // 64B-aligned run
    __syncthreads();
    #pragma unroll
    for (int j = 0; j < 8; ++j) {
        if (bkt[j] >= 0)
            staging[bbase[bkt[j]] + lpos[j]] = make_uint2((uint_t)sr[j], pay[j]);
    }
    // sentinel-fill the pad (same line as the run's tail -> L2-hot)
    if (c > 0) {
        int padto = (c + 7) & ~7;
        for (int p = c; p < padto; ++p)
            staging[bbase[tid] + p] = make_uint2(0xFFFFFFFFu, 0u);
    }
}

// Phase B: one 256-thread WG per bucket. LDS histogram from staging (skipping
// sentinels), LDS padded prefix scan -> local row bases, scatter into the
// bucket's PRIVATE csr slice, emit per-row (beg,end) pairs, degree-sorted perm,
// zero pad slots.
__global__ __launch_bounds__(256) void
binB_kernel(const uint2* __restrict__ staging, const int* __restrict__ gcur,
            int2* __restrict__ rp, int* __restrict__ perm,
            uint_t* __restrict__ csr, int n) {
    __shared__ int lcnt[256];
    __shared__ int lbeg[256];
    __shared__ int lcur[256];
    __shared__ int wsum[4];
    __shared__ int ccls[16];
    __shared__ int cbase2[16];
    const int tid = threadIdx.x;
    const int b = blockIdx.x;
    const int r0 = b << BKT_SHIFT;
    lcnt[tid] = 0;
    lcur[tid] = 0;
    if (tid < 16) ccls[tid] = 0;
    __syncthreads();
    const int s0 = b * BKT_CAP;
    const int cb = gcur[b] - s0;
    for (int i = tid; i < cb; i += 256) {
        unsigned li = staging[s0 + i].x - (unsigned)r0;
        if (li < 256u) atomicAdd(&lcnt[(int)li], 1);
    }
    __syncthreads();
    // padded inclusive scan over 256 counts (4 waves)
    const int lane = tid & 63;
    const int wv = tid >> 6;
    int padded = (lcnt[tid] + 7) & ~7;
    int s = padded;
    #pragma unroll
    for (int off = 1; off < 64; off <<= 1) {
        int u = __shfl_up(s, off, 64);
        if (lane >= off) s += u;
    }
    if (lane == 63) wsum[wv] = s;
    __syncthreads();
    if (tid == 0) {
        int a = 0;
        #pragma unroll
        for (int j = 0; j < 4; ++j) { int t = wsum[j]; wsum[j] = a; a += t; }
    }
    __syncthreads();
    int beg = wsum[wv] + s - padded;  // exclusive padded prefix
    lbeg[tid] = beg;
    // degree-class histogram -> perm (wave load balance in taylor)
    int r = r0 + tid;
    int cls = min(padded >> 4, 15);
    if (r < n) atomicAdd(&ccls[cls], 1);
    __syncthreads();
    if (tid == 0) {
        int a = 0;
        #pragma unroll
        for (int j = 0; j < 16; ++j) { int t = ccls[j]; cbase2[j] = a; a += t; }
    }
    __syncthreads();
    if (tid < 16) ccls[tid] = 0;
    __syncthreads();
    if (r < n) {
        int slot = cbase2[cls] + atomicAdd(&ccls[cls], 1);
        perm[r0 + slot] = r;
    }
    __syncthreads();
    const int cbase = b * CSR_CAP;
    for (int i = tid; i < cb; i += 256) {
        uint2 e = staging[s0 + i];
        unsigned li = e.x - (unsigned)r0;
        if (li < 256u) {
            int p = cbase + lbeg[(int)li] + atomicAdd(&lcur[(int)li], 1);
            csr[p] = e.y;
        }
    }
    __syncthreads();
    if (r < n) {
        rp[r] = make_int2(cbase + beg, cbase + beg + padded);
        for (int p = cbase + beg + lcnt[tid]; p < cbase + beg + padded; ++p)
            csr[p] = 0;
    }
}

// ---- fallback path (small ws): global hist + scans + atomic scatter ----
__global__ void hist_kernel(const int* __restrict__ src, int* __restrict__ cnt, int E) {
    int e = blockIdx.x * blockDim.x + threadIdx.x;
    if (e < E) atomicAdd(&cnt[src[e]], 1);
}

__global__ void scan1_kernel(const int* __restrict__ cnt, int* __restrict__ row_ptr,
                             int* __restrict__ blk_sum, int n) {
    __shared__ int wsum[16];
    const int tid = threadIdx.x;
    const int lane = tid & 63;
    const int wv = tid >> 6;
    int i = blockIdx.x * 1024 + tid;
    int vr = (i < n) ? cnt[i] : 0;
    int v = (vr + 7) & ~7;
    int s = v;
    #pragma unroll
    for (int off = 1; off < 64; off <<= 1) {
        int u = __shfl_up(s, off, 64);
        if (lane >= off) s += u;
    }
    if (lane == 63) wsum[wv] = s;
    __syncthreads();
    if (wv == 0) {
        int ws = (lane < 16) ? wsum[lane] : 0;
        #pragma unroll
        for (int off = 1; off < 16; off <<= 1) {
            int u = __shfl_up(ws, off, 64);
            if (lane >= off) ws += u;
        }
        if (lane < 16) wsum[lane] = ws;
    }
    __syncthreads();
    int incl = s + ((wv == 0) ? 0 : wsum[wv - 1]);
    if (i < n) row_ptr[i + 1] = incl;
    if (tid == 1023) blk_sum[blockIdx.x] = incl;
}

__global__ void scan3_kernel(int* __restrict__ row_ptr, int* __restrict__ pos,
                             int2* __restrict__ rp, int* __restrict__ perm,
                             const int* __restrict__ blk_sum,
                             const int* __restrict__ cnt, int n, int nb) {
    __shared__ int soff[64];
    const int tid = threadIdx.x;
    if (tid < 64) {
        int v = (tid < nb) ? blk_sum[tid] : 0;
        int s = v;
        #pragma unroll
        for (int off = 1; off < 64; off <<= 1) {
            int u = __shfl_up(s, off, 64);
            if (tid >= off) s += u;
        }
        soff[tid] = s - v;
    }
    __syncthreads();
    int i = blockIdx.x * blockDim.x + tid;
    if (i < n) {
        int incl = row_ptr[i + 1] + soff[i >> 10];
        int padded = (cnt[i] + 7) & ~7;
        pos[i] = incl - padded;
        rp[i] = make_int2(incl - padded, incl);
        perm[i] = i;
    }
}

__global__ void scatter_kernel(const int* __restrict__ src, const int* __restrict__ dst,
                               const float* __restrict__ w, int* __restrict__ pos,
                               uint_t* __restrict__ csr, int E) {
    int e = blockIdx.x * blockDim.x + threadIdx.x;
    if (e < E) {
        int r = src[e];
        int p = atomicAdd(&pos[r], 1);
        csr[p] = (uint_t)dst[e] | ((uint_t)f2bf(w[e]) << 16);
    }
}

// ---------------- diffusion ----------------
// 8 lanes per row x uint4 (8 bf16 ch) = 128B row; 8 rows/wave via degree-sorted
// perm; 16-wide iteration; cooperative csr load (1/lane) + ds_swizzle broadcast.
// mode: 0 term only; 1 first+acc; 2 acc RMW; 3 FINAL.

__global__ __launch_bounds__(256) void
taylor_kernel(const int2* __restrict__ rp, const int* __restrict__ perm,
              const uint_t* __restrict__ csr,
              const uint4* __restrict__ term_in, uint4* __restrict__ term_out,
              float4* __restrict__ acc, const float4* __restrict__ x,
              const uint4* __restrict__ terms_all, size_t term_stride,
              const float* __restrict__ t_ptr,
              float inv_k, int n, int mode) {
    int gid = blockIdx.x * blockDim.x + threadIdx.x;
    int slot = gid >> 3;
    if (slot >= n) return;
    int row = perm[slot];
    int lane = gid & 7;
    float t = fmaxf(t_ptr[0], 1e-8f);
    float coef = -t * inv_k;
    int2 be = rp[row];
    int beg = be.x;
    int end = be.y;   // (end - beg) % 8 == 0

    float c0 = 0.f, c1 = 0.f, c2 = 0.f, c3 = 0.f;
    float c4 = 0.f, c5 = 0.f, c6 = 0.f, c7 = 0.f;
    for (int e = beg; e < end; e += 16) {
        int eB = e + 8;
        bool hasB = eB < end;
        uint_t mA = csr[e + lane];
        uint_t mB = csr[(hasB ? eB : e) + lane];   // re-read A when no B (wB=0)
        uint_t a0 = BCAST(mA, 0), a1 = BCAST(mA, 1), a2 = BCAST(mA, 2), a3 = BCAST(mA, 3);
        uint_t a4 = BCAST(mA, 4), a5 = BCAST(mA, 5), a6 = BCAST(mA, 6), a7 = BCAST(mA, 7);
        uint_t b0 = BCAST(mB, 0), b1 = BCAST(mB, 1), b2 = BCAST(mB, 2), b3 = BCAST(mB, 3);
        uint_t b4 = BCAST(mB, 4), b5 = BCAST(mB, 5), b6 = BCAST(mB, 6), b7 = BCAST(mB, 7);
        uint4 vA0 = term_in[(size_t)(a0 & 0xFFFFu) * 8 + lane];
        uint4 vA1 = term_in[(size_t)(a1 & 0xFFFFu) * 8 + lane];
        uint4 vA2 = term_in[(size_t)(a2 & 0xFFFFu) * 8 + lane];
        uint4 vA3 = term_in[(size_t)(a3 & 0xFFFFu) * 8 + lane];
        uint4 vA4 = term_in[(size_t)(a4 & 0xFFFFu) * 8 + lane];
        uint4 vA5 = term_in[(size_t)(a5 & 0xFFFFu) * 8 + lane];
        uint4 vA6 = term_in[(size_t)(a6 & 0xFFFFu) * 8 + lane];
        uint4 vA7 = term_in[(size_t)(a7 & 0xFFFFu) * 8 + lane];
        uint4 vB0 = term_in[(size_t)(b0 & 0xFFFFu) * 8 + lane];
        uint4 vB1 = term_in[(size_t)(b1 & 0xFFFFu) * 8 + lane];
        uint4 vB2 = term_in[(size_t)(b2 & 0xFFFFu) * 8 + lane];
        uint4 vB3 = term_in[(size_t)(b3 & 0xFFFFu) * 8 + lane];
        uint4 vB4 = term_in[(size_t)(b4 & 0xFFFFu) * 8 + lane];
        uint4 vB5 = term_in[(size_t)(b5 & 0xFFFFu) * 8 + lane];
        uint4 vB6 = term_in[(size_t)(b6 & 0xFFFFu) * 8 + lane];
        uint4 vB7 = term_in[(size_t)(b7 & 0xFFFFu) * 8 + lane];
        float fB = hasB ? 1.f : 0.f;
        #define FMA8(W, V)                              \
            c0 = fmaf(W, bf2f((V).x & 0xFFFFu), c0);    \
            c1 = fmaf(W, bf2f((V).x >> 16),     c1);    \
            c2 = fmaf(W, bf2f((V).y & 0xFFFFu), c2);    \
            c3 = fmaf(W, bf2f((V).y >> 16),     c3);    \
            c4 = fmaf(W, bf2f((V).z & 0xFFFFu), c4);    \
            c5 = fmaf(W, bf2f((V).z >> 16),     c5);    \
            c6 = fmaf(W, bf2f((V).w & 0xFFFFu), c6);    \
            c7 = fmaf(W, bf2f((V).w >> 16),     c7);
        FMA8(bf2f(a0 >> 16), vA0)
        FMA8(bf2f(a1 >> 16), vA1)
        FMA8(bf2f(a2 >> 16), vA2)
        FMA8(bf2f(a3 >> 16), vA3)
        FMA8(bf2f(a4 >> 16), vA4)
        FMA8(bf2f(a5 >> 16), vA5)
        FMA8(bf2f(a6 >> 16), vA6)
        FMA8(bf2f(a7 >> 16), vA7)
        FMA8(fB * bf2f(b0 >> 16), vB0)
        FMA8(fB * bf2f(b1 >> 16), vB1)
        FMA8(fB * bf2f(b2 >> 16), vB2)
        FMA8(fB * bf2f(b3 >> 16), vB3)
        FMA8(fB * bf2f(b4 >> 16), vB4)
        FMA8(fB * bf2f(b5 >> 16), vB5)
        FMA8(fB * bf2f(b6 >> 16), vB6)
        FMA8(fB * bf2f(b7 >> 16), vB7)
        #undef FMA8
    }
    c0 *= coef; c1 *= coef; c2 *= coef; c3 *= coef;
    c4 *= coef; c5 *= coef; c6 *= coef; c7 *= coef;
    size_t idx = (size_t)row * 8 + lane;
    if (mode != 3) {
        term_out[idx] = make_uint4((uint_t)f2bf(c0) | ((uint_t)f2bf(c1) << 16),
                                   (uint_t)f2bf(c2) | ((uint_t)f2bf(c3) << 16),
                                   (uint_t)f2bf(c4) | ((uint_t)f2bf(c5) << 16),
                                   (uint_t)f2bf(c6) | ((uint_t)f2bf(c7) << 16));
    }
    if (mode == 1) {
        size_t fi = (size_t)row * 16 + lane * 2;
        float4 xa = x[fi], xb4 = x[fi + 1];
        acc[fi]     = make_float4(xa.x + c0, xa.y + c1, xa.z + c2, xa.w + c3);
        acc[fi + 1] = make_float4(xb4.x + c4, xb4.y + c5, xb4.z + c6, xb4.w + c7);
    } else if (mode == 2) {
        size_t fi = (size_t)row * 16 + lane * 2;
        float4 aa = acc[fi], ab = acc[fi + 1];
        acc[fi]     = make_float4(aa.x + c0, aa.y + c1, aa.z + c2, aa.w + c3);
        acc[fi + 1] = make_float4(ab.x + c4, ab.y + c5, ab.z + c6, ab.w + c7);
    } else if (mode == 3) {
        float s0 = c0, s1 = c1, s2 = c2, s3 = c3;
        float s4 = c4, s5 = c5, s6 = c6, s7 = c7;
        #pragma unroll
        for (int j = 0; j < M_TERMS - 1; ++j) {
            uint4 tv = terms_all[(size_t)j * term_stride + idx];
            s0 += bf2f(tv.x & 0xFFFFu);
            s1 += bf2f(tv.x >> 16);
            s2 += bf2f(tv.y & 0xFFFFu);
            s3 += bf2f(tv.y >> 16);
            s4 += bf2f(tv.z & 0xFFFFu);
            s5 += bf2f(tv.z >> 16);
            s6 += bf2f(tv.w & 0xFFFFu);
            s7 += bf2f(tv.w >> 16);
        }
        size_t fi = (size_t)row * 16 + lane * 2;
        float4 xa = x[fi], xb4 = x[fi + 1];
        acc[fi]     = make_float4(xa.x + s0, xa.y + s1, xa.z + s2, xa.w + s3);
        acc[fi + 1] = make_float4(xb4.x + s4, xb4.y + s5, xb4.z + s6, xb4.w + s7);
    }
}

extern "C" void kernel_launch(void* const* d_in, const int* in_sizes, int n_in,
                              void* d_out, int out_size, void* d_ws, size_t ws_size,
                              hipStream_t stream) {
    const float* x    = (const float*)d_in[0];
    const int*   esrc = (const int*)d_in[1];
    const int*   edst = (const int*)d_in[2];
    const float* ew   = (const float*)d_in[3];
    const float* tp   = (const float*)d_in[4];
    float* out = (float*)d_out;

    const int E = in_sizes[1];
    const int N = N_NODES;
    const int NC = N * C_CH;
    const size_t TERM4 = (size_t)NC / 8;            // uint4 per term buffer
    const int nb = (N + BKT_ROWS - 1) / BKT_ROWS;   // 196 buckets

    int* ws = (int*)d_ws;
    int2* rp     = (int2*)ws;                   // N pairs -> 100000, pad 100096
    int* perm    = ws + 100096;                 // N -> 150144
    int* cnt     = ws + 150144;                 // N (fallback) -> 200192
    int* row_ptr = ws + 200192;                 // N+1 (fallback) -> 250240
    int* pos     = ws + 250240;                 // N (fallback) -> 300288
    int* blk_sum = ws + 300288;                 // 64
    int* gcur    = ws + 300352;                 // 256 -> 300608, pad 300672
    uint_t* csr  = (uint_t*)(ws + 300672);      // nb*CSR_CAP entries
    size_t stag_off = 300672 + (size_t)nb * CSR_CAP;
    stag_off = (stag_off + 1) & ~(size_t)1;
    uint2* staging = (uint2*)(ws + stag_off);   // nb*BKT_CAP uint2
    size_t xb_off = (stag_off + 2 * (size_t)nb * BKT_CAP + 3) & ~(size_t)3;
    uint4* xb = (uint4*)(ws + xb_off);          // TERM4 (16B aligned)

    const size_t needA = (xb_off + (size_t)M_TERMS * TERM4 * 4) * 4;
    const int pathA = (ws_size >= needA);

    cvt_kernel<<<(NC / 8 + 255) / 256, 256, 0, stream>>>((const float4*)x, xb,
                                                         NC / 8, gcur);
    if (pathA) {
        binA_kernel<<<(E + 2047) / 2048, 256, 0, stream>>>(esrc, edst, ew, gcur,
                                                           staging, E);
        binB_kernel<<<nb, 256, 0, stream>>>(staging, gcur, rp, perm, csr, N);
    } else {
        hipMemsetAsync(cnt, 0, (size_t)N * sizeof(int), stream);
        hist_kernel<<<(E + 255) / 256, 256, 0, stream>>>(esrc, cnt, E);
        const int nsb = (N + 1023) / 1024;
        scan1_kernel<<<nsb, 1024, 0, stream>>>(cnt, row_ptr, blk_sum, N);
        scan3_kernel<<<(N + 255) / 256, 256, 0, stream>>>(row_ptr, pos, rp, perm,
                                                          blk_sum, cnt, N, nsb);
        hipMemsetAsync(csr, 0, (size_t)nb * CSR_CAP * sizeof(uint_t), stream);
        scatter_kernel<<<(E + 255) / 256, 256, 0, stream>>>(esrc, edst, ew, pos, csr, E);
    }

    const int tgrid = (N * 8 + 255) / 256;   // 8 lanes per row

    if (pathA) {
        uint4* terms = xb + TERM4;  // M_TERMS-1 consecutive buffers
        taylor_kernel<<<tgrid, 256, 0, stream>>>(rp, perm, csr, xb, terms, nullptr,
                                                 nullptr, nullptr, 0, tp, 1.0f, N, 0);
        for (int k = 2; k <= M_TERMS - 1; ++k) {
            taylor_kernel<<<tgrid, 256, 0, stream>>>(rp, perm, csr,
                                                     terms + (size_t)(k - 2) * TERM4,
                                                     terms + (size_t)(k - 1) * TERM4,
                                                     nullptr, nullptr, nullptr, 0,
                                                     tp, 1.0f / (float)k, N, 0);
        }
        taylor_kernel<<<tgrid, 256, 0, stream>>>(rp, perm, csr,
                                                 terms + (size_t)(M_TERMS - 2) * TERM4,
                                                 terms, (float4*)out, (const float4*)x,
                                                 terms, TERM4,
                                                 tp, 1.0f / (float)M_TERMS, N, 3);
    } else {
        uint4* term_a = xb + TERM4;
        uint4* term_b = term_a + TERM4;
        taylor_kernel<<<tgrid, 256, 0, stream>>>(rp, perm, csr, xb, term_b,
                                                 (float4*)out, (const float4*)x,
                                                 nullptr, 0, tp, 1.0f, N, 1);
        const uint4* tin = term_b;
        uint4* tout = term_a;
        for (int k = 2; k <= M_TERMS; ++k) {
            taylor_kernel<<<tgrid, 256, 0, stream>>>(rp, perm, csr, tin, tout,
                                                     (float4*)out, (const float4*)x,
                                                     nullptr, 0, tp,
                                                     1.0f / (float)k, N, 2);
            const uint4* tmp = tin;
            tin = tout;
            tout = (uint4*)tmp;
        }
    }
}

// Round 18
// 94.558 us; speedup vs baseline: 1.3442x; 1.0629x over previous
//
#include <hip/hip_runtime.h>

#define N_NODES 50000
#define C_CH 64
#define M_TERMS 3      // ||-t*L||inf <= ~0.52 worst row; tail after 3 terms ~0.017 abs
#define BKT_SHIFT 8
#define BKT_ROWS 256   // rows per bucket
#define BKT_CAP 5120   // staging cap per bucket (mean 4081, +16 sigma)
#define CSR_CAP 6912   // padded csr slice per bucket
#define SEG_A 4096     // edges per binA block (long runs -> fewer shared-line boundaries)

typedef unsigned short ushort_t;
typedef unsigned int uint_t;

__device__ __forceinline__ float bf2f(uint_t h16) {  // low 16 bits = bf16
    return __uint_as_float(h16 << 16);
}
__device__ __forceinline__ ushort_t f2bf(float f) {  // round-to-nearest-even
    uint_t u = __float_as_uint(f);
    u += 0x7FFFu + ((u >> 16) & 1u);
    return (ushort_t)(u >> 16);
}

// broadcast csr entry j to all lanes of each 8-lane group:
// BitMode target = (lane & 0x18) | j  -> offset = (j << 5) | 0x18
#define BCAST(M, J) ((uint_t)__builtin_amdgcn_ds_swizzle((int)(M), (((J) << 5) | 0x18)))

// ---------------- CSR build ----------------

// tiny: init bucket cursors (must precede binA)
__global__ void init_kernel(int* __restrict__ gcur) {
    if (threadIdx.x < 256) gcur[threadIdx.x] = threadIdx.x * BKT_CAP;
}

// FUSED binA + cvt: blocks [0, nblkA) bin edges by src>>8 into bucket-contiguous
// staging (4096 edges/block -> long runs); blocks [nblkA, ...) convert x->bf16x8.
// Disjoint block ranges run concurrently — cvt fills CUs idle under binA's
// latency/atomic-bound phase.
__global__ __launch_bounds__(256) void
binA_cvt_kernel(const int* __restrict__ src, const int* __restrict__ dst,
                const float* __restrict__ w, int* __restrict__ gcur,
                uint2* __restrict__ staging, int E, int nblkA,
                const float4* __restrict__ x, uint4* __restrict__ xb, int n8) {
    const int tid = threadIdx.x;
    if ((int)blockIdx.x >= nblkA) {
        int i = ((int)blockIdx.x - nblkA) * 256 + tid;
        if (i < n8) {
            float4 a = x[2 * i], b = x[2 * i + 1];
            xb[i] = make_uint4((uint_t)f2bf(a.x) | ((uint_t)f2bf(a.y) << 16),
                               (uint_t)f2bf(a.z) | ((uint_t)f2bf(a.w) << 16),
                               (uint_t)f2bf(b.x) | ((uint_t)f2bf(b.y) << 16),
                               (uint_t)f2bf(b.z) | ((uint_t)f2bf(b.w) << 16));
        }
        return;
    }
    __shared__ int bcnt[256];
    __shared__ int bbase[256];
    const int base = blockIdx.x * SEG_A;
    bcnt[tid] = 0;
    __syncthreads();
    int lpos[16], bkt[16], sr[16];
    uint_t pay[16];
    #pragma unroll
    for (int j = 0; j < 16; ++j) {
        int e = base + j * 256 + tid;
        if (e < E) {
            int s = src[e];
            int b = s >> BKT_SHIFT;
            sr[j] = s;
            bkt[j] = b;
            pay[j] = (uint_t)dst[e] | ((uint_t)f2bf(w[e]) << 16);
            lpos[j] = atomicAdd(&bcnt[b], 1);
        } else {
            bkt[j] = -1;
        }
    }
    __syncthreads();
    if (bcnt[tid] > 0) bbase[tid] = atomicAdd(&gcur[tid], bcnt[tid]);
    __syncthreads();
    #pragma unroll
    for (int j = 0; j < 16; ++j) {
        if (bkt[j] >= 0)
            staging[bbase[bkt[j]] + lpos[j]] = make_uint2((uint_t)sr[j], pay[j]);
    }
}

// Phase B: one 256-thread WG per bucket. LDS histogram from staging, LDS padded
// prefix scan -> local row bases, scatter into the bucket's PRIVATE csr slice,
// emit per-row (beg,end) pairs, degree-sorted perm, zero pad slots.
__global__ __launch_bounds__(256) void
binB_kernel(const uint2* __restrict__ staging, const int* __restrict__ gcur,
            int2* __restrict__ rp, int* __restrict__ perm,
            uint_t* __restrict__ csr, int n) {
    __shared__ int lcnt[256];
    __shared__ int lbeg[256];
    __shared__ int lcur[256];
    __shared__ int wsum[4];
    __shared__ int ccls[16];
    __shared__ int cbase2[16];
    const int tid = threadIdx.x;
    const int b = blockIdx.x;
    const int r0 = b << BKT_SHIFT;
    lcnt[tid] = 0;
    lcur[tid] = 0;
    if (tid < 16) ccls[tid] = 0;
    __syncthreads();
    const int s0 = b * BKT_CAP;
    const int cb = gcur[b] - s0;
    for (int i = tid; i < cb; i += 256)
        atomicAdd(&lcnt[(int)staging[s0 + i].x - r0], 1);
    __syncthreads();
    // padded inclusive scan over 256 counts (4 waves)
    const int lane = tid & 63;
    const int wv = tid >> 6;
    int padded = (lcnt[tid] + 7) & ~7;
    int s = padded;
    #pragma unroll
    for (int off = 1; off < 64; off <<= 1) {
        int u = __shfl_up(s, off, 64);
        if (lane >= off) s += u;
    }
    if (lane == 63) wsum[wv] = s;
    __syncthreads();
    if (tid == 0) {
        int a = 0;
        #pragma unroll
        for (int j = 0; j < 4; ++j) { int t = wsum[j]; wsum[j] = a; a += t; }
    }
    __syncthreads();
    int beg = wsum[wv] + s - padded;  // exclusive padded prefix
    lbeg[tid] = beg;
    // degree-class histogram -> perm (wave load balance in taylor)
    int r = r0 + tid;
    int cls = min(padded >> 4, 15);
    if (r < n) atomicAdd(&ccls[cls], 1);
    __syncthreads();
    if (tid == 0) {
        int a = 0;
        #pragma unroll
        for (int j = 0; j < 16; ++j) { int t = ccls[j]; cbase2[j] = a; a += t; }
    }
    __syncthreads();
    if (tid < 16) ccls[tid] = 0;
    __syncthreads();
    if (r < n) {
        int slot = cbase2[cls] + atomicAdd(&ccls[cls], 1);
        perm[r0 + slot] = r;
    }
    __syncthreads();
    const int cbase = b * CSR_CAP;
    for (int i = tid; i < cb; i += 256) {
        uint2 e = staging[s0 + i];
        int li = (int)e.x - r0;
        int p = cbase + lbeg[li] + atomicAdd(&lcur[li], 1);
        csr[p] = e.y;
    }
    __syncthreads();
    if (r < n) {
        rp[r] = make_int2(cbase + beg, cbase + beg + padded);
        for (int p = cbase + beg + lcnt[tid]; p < cbase + beg + padded; ++p)
            csr[p] = 0;
    }
}

// ---- fallback path (small ws): global hist + scans + atomic scatter ----
__global__ void hist_kernel(const int* __restrict__ src, int* __restrict__ cnt, int E) {
    int e = blockIdx.x * blockDim.x + threadIdx.x;
    if (e < E) atomicAdd(&cnt[src[e]], 1);
}

__global__ void scan1_kernel(const int* __restrict__ cnt, int* __restrict__ row_ptr,
                             int* __restrict__ blk_sum, int n) {
    __shared__ int wsum[16];
    const int tid = threadIdx.x;
    const int lane = tid & 63;
    const int wv = tid >> 6;
    int i = blockIdx.x * 1024 + tid;
    int vr = (i < n) ? cnt[i] : 0;
    int v = (vr + 7) & ~7;
    int s = v;
    #pragma unroll
    for (int off = 1; off < 64; off <<= 1) {
        int u = __shfl_up(s, off, 64);
        if (lane >= off) s += u;
    }
    if (lane == 63) wsum[wv] = s;
    __syncthreads();
    if (wv == 0) {
        int ws = (lane < 16) ? wsum[lane] : 0;
        #pragma unroll
        for (int off = 1; off < 16; off <<= 1) {
            int u = __shfl_up(ws, off, 64);
            if (lane >= off) ws += u;
        }
        if (lane < 16) wsum[lane] = ws;
    }
    __syncthreads();
    int incl = s + ((wv == 0) ? 0 : wsum[wv - 1]);
    if (i < n) row_ptr[i + 1] = incl;
    if (tid == 1023) blk_sum[blockIdx.x] = incl;
}

__global__ void scan3_kernel(int* __restrict__ row_ptr, int* __restrict__ pos,
                             int2* __restrict__ rp, int* __restrict__ perm,
                             const int* __restrict__ blk_sum,
                             const int* __restrict__ cnt, int n, int nb) {
    __shared__ int soff[64];
    const int tid = threadIdx.x;
    if (tid < 64) {
        int v = (tid < nb) ? blk_sum[tid] : 0;
        int s = v;
        #pragma unroll
        for (int off = 1; off < 64; off <<= 1) {
            int u = __shfl_up(s, off, 64);
            if (tid >= off) s += u;
        }
        soff[tid] = s - v;
    }
    __syncthreads();
    int i = blockIdx.x * blockDim.x + tid;
    if (i < n) {
        int incl = row_ptr[i + 1] + soff[i >> 10];
        int padded = (cnt[i] + 7) & ~7;
        pos[i] = incl - padded;
        rp[i] = make_int2(incl - padded, incl);
        perm[i] = i;
    }
}

__global__ void scatter_kernel(const int* __restrict__ src, const int* __restrict__ dst,
                               const float* __restrict__ w, int* __restrict__ pos,
                               uint_t* __restrict__ csr, int E) {
    int e = blockIdx.x * blockDim.x + threadIdx.x;
    if (e < E) {
        int r = src[e];
        int p = atomicAdd(&pos[r], 1);
        csr[p] = (uint_t)dst[e] | ((uint_t)f2bf(w[e]) << 16);
    }
}

// ---------------- diffusion ----------------
// 8 lanes per row x uint4 (8 bf16 ch) = 128B row; 8 rows/wave via degree-sorted
// perm; 16-wide iteration; cooperative csr load (1/lane) + ds_swizzle broadcast.
// mode: 0 term only; 1 first+acc; 2 acc RMW; 3 FINAL.

__global__ __launch_bounds__(256) void
taylor_kernel(const int2* __restrict__ rp, const int* __restrict__ perm,
              const uint_t* __restrict__ csr,
              const uint4* __restrict__ term_in, uint4* __restrict__ term_out,
              float4* __restrict__ acc, const float4* __restrict__ x,
              const uint4* __restrict__ terms_all, size_t term_stride,
              const float* __restrict__ t_ptr,
              float inv_k, int n, int mode) {
    int gid = blockIdx.x * blockDim.x + threadIdx.x;
    int slot = gid >> 3;
    if (slot >= n) return;
    int row = perm[slot];
    int lane = gid & 7;
    float t = fmaxf(t_ptr[0], 1e-8f);
    float coef = -t * inv_k;
    int2 be = rp[row];
    int beg = be.x;
    int end = be.y;   // (end - beg) % 8 == 0

    float c0 = 0.f, c1 = 0.f, c2 = 0.f, c3 = 0.f;
    float c4 = 0.f, c5 = 0.f, c6 = 0.f, c7 = 0.f;
    for (int e = beg; e < end; e += 16) {
        int eB = e + 8;
        bool hasB = eB < end;
        uint_t mA = csr[e + lane];
        uint_t mB = csr[(hasB ? eB : e) + lane];   // re-read A when no B (wB=0)
        uint_t a0 = BCAST(mA, 0), a1 = BCAST(mA, 1), a2 = BCAST(mA, 2), a3 = BCAST(mA, 3);
        uint_t a4 = BCAST(mA, 4), a5 = BCAST(mA, 5), a6 = BCAST(mA, 6), a7 = BCAST(mA, 7);
        uint_t b0 = BCAST(mB, 0), b1 = BCAST(mB, 1), b2 = BCAST(mB, 2), b3 = BCAST(mB, 3);
        uint_t b4 = BCAST(mB, 4), b5 = BCAST(mB, 5), b6 = BCAST(mB, 6), b7 = BCAST(mB, 7);
        uint4 vA0 = term_in[(size_t)(a0 & 0xFFFFu) * 8 + lane];
        uint4 vA1 = term_in[(size_t)(a1 & 0xFFFFu) * 8 + lane];
        uint4 vA2 = term_in[(size_t)(a2 & 0xFFFFu) * 8 + lane];
        uint4 vA3 = term_in[(size_t)(a3 & 0xFFFFu) * 8 + lane];
        uint4 vA4 = term_in[(size_t)(a4 & 0xFFFFu) * 8 + lane];
        uint4 vA5 = term_in[(size_t)(a5 & 0xFFFFu) * 8 + lane];
        uint4 vA6 = term_in[(size_t)(a6 & 0xFFFFu) * 8 + lane];
        uint4 vA7 = term_in[(size_t)(a7 & 0xFFFFu) * 8 + lane];
        uint4 vB0 = term_in[(size_t)(b0 & 0xFFFFu) * 8 + lane];
        uint4 vB1 = term_in[(size_t)(b1 & 0xFFFFu) * 8 + lane];
        uint4 vB2 = term_in[(size_t)(b2 & 0xFFFFu) * 8 + lane];
        uint4 vB3 = term_in[(size_t)(b3 & 0xFFFFu) * 8 + lane];
        uint4 vB4 = term_in[(size_t)(b4 & 0xFFFFu) * 8 + lane];
        uint4 vB5 = term_in[(size_t)(b5 & 0xFFFFu) * 8 + lane];
        uint4 vB6 = term_in[(size_t)(b6 & 0xFFFFu) * 8 + lane];
        uint4 vB7 = term_in[(size_t)(b7 & 0xFFFFu) * 8 + lane];
        float fB = hasB ? 1.f : 0.f;
        #define FMA8(W, V)                              \
            c0 = fmaf(W, bf2f((V).x & 0xFFFFu), c0);    \
            c1 = fmaf(W, bf2f((V).x >> 16),     c1);    \
            c2 = fmaf(W, bf2f((V).y & 0xFFFFu), c2);    \
            c3 = fmaf(W, bf2f((V).y >> 16),     c3);    \
            c4 = fmaf(W, bf2f((V).z & 0xFFFFu), c4);    \
            c5 = fmaf(W, bf2f((V).z >> 16),     c5);    \
            c6 = fmaf(W, bf2f((V).w & 0xFFFFu), c6);    \
            c7 = fmaf(W, bf2f((V).w >> 16),     c7);
        FMA8(bf2f(a0 >> 16), vA0)
        FMA8(bf2f(a1 >> 16), vA1)
        FMA8(bf2f(a2 >> 16), vA2)
        FMA8(bf2f(a3 >> 16), vA3)
        FMA8(bf2f(a4 >> 16), vA4)
        FMA8(bf2f(a5 >> 16), vA5)
        FMA8(bf2f(a6 >> 16), vA6)
        FMA8(bf2f(a7 >> 16), vA7)
        FMA8(fB * bf2f(b0 >> 16), vB0)
        FMA8(fB * bf2f(b1 >> 16), vB1)
        FMA8(fB * bf2f(b2 >> 16), vB2)
        FMA8(fB * bf2f(b3 >> 16), vB3)
        FMA8(fB * bf2f(b4 >> 16), vB4)
        FMA8(fB * bf2f(b5 >> 16), vB5)
        FMA8(fB * bf2f(b6 >> 16), vB6)
        FMA8(fB * bf2f(b7 >> 16), vB7)
        #undef FMA8
    }
    c0 *= coef; c1 *= coef; c2 *= coef; c3 *= coef;
    c4 *= coef; c5 *= coef; c6 *= coef; c7 *= coef;
    size_t idx = (size_t)row * 8 + lane;
    if (mode != 3) {
        term_out[idx] = make_uint4((uint_t)f2bf(c0) | ((uint_t)f2bf(c1) << 16),
                                   (uint_t)f2bf(c2) | ((uint_t)f2bf(c3) << 16),
                                   (uint_t)f2bf(c4) | ((uint_t)f2bf(c5) << 16),
                                   (uint_t)f2bf(c6) | ((uint_t)f2bf(c7) << 16));
    }
    if (mode == 1) {
        size_t fi = (size_t)row * 16 + lane * 2;
        float4 xa = x[fi], xb4 = x[fi + 1];
        acc[fi]     = make_float4(xa.x + c0, xa.y + c1, xa.z + c2, xa.w + c3);
        acc[fi + 1] = make_float4(xb4.x + c4, xb4.y + c5, xb4.z + c6, xb4.w + c7);
    } else if (mode == 2) {
        size_t fi = (size_t)row * 16 + lane * 2;
        float4 aa = acc[fi], ab = acc[fi + 1];
        acc[fi]     = make_float4(aa.x + c0, aa.y + c1, aa.z + c2, aa.w + c3);
        acc[fi + 1] = make_float4(ab.x + c4, ab.y + c5, ab.z + c6, ab.w + c7);
    } else if (mode == 3) {
        float s0 = c0, s1 = c1, s2 = c2, s3 = c3;
        float s4 = c4, s5 = c5, s6 = c6, s7 = c7;
        #pragma unroll
        for (int j = 0; j < M_TERMS - 1; ++j) {
            uint4 tv = terms_all[(size_t)j * term_stride + idx];
            s0 += bf2f(tv.x & 0xFFFFu);
            s1 += bf2f(tv.x >> 16);
            s2 += bf2f(tv.y & 0xFFFFu);
            s3 += bf2f(tv.y >> 16);
            s4 += bf2f(tv.z & 0xFFFFu);
            s5 += bf2f(tv.z >> 16);
            s6 += bf2f(tv.w & 0xFFFFu);
            s7 += bf2f(tv.w >> 16);
        }
        size_t fi = (size_t)row * 16 + lane * 2;
        float4 xa = x[fi], xb4 = x[fi + 1];
        acc[fi]     = make_float4(xa.x + s0, xa.y + s1, xa.z + s2, xa.w + s3);
        acc[fi + 1] = make_float4(xb4.x + s4, xb4.y + s5, xb4.z + s6, xb4.w + s7);
    }
}

extern "C" void kernel_launch(void* const* d_in, const int* in_sizes, int n_in,
                              void* d_out, int out_size, void* d_ws, size_t ws_size,
                              hipStream_t stream) {
    const float* x    = (const float*)d_in[0];
    const int*   esrc = (const int*)d_in[1];
    const int*   edst = (const int*)d_in[2];
    const float* ew   = (const float*)d_in[3];
    const float* tp   = (const float*)d_in[4];
    float* out = (float*)d_out;

    const int E = in_sizes[1];
    const int N = N_NODES;
    const int NC = N * C_CH;
    const size_t TERM4 = (size_t)NC / 8;            // uint4 per term buffer
    const int nb = (N + BKT_ROWS - 1) / BKT_ROWS;   // 196 buckets
    const int nblkA = (E + SEG_A - 1) / SEG_A;      // 196 binA blocks
    const int ncvt = (NC / 8 + 255) / 256;          // cvt blocks

    int* ws = (int*)d_ws;
    int2* rp     = (int2*)ws;                   // N pairs -> 100000, pad 100096
    int* perm    = ws + 100096;                 // N -> 150144
    int* cnt     = ws + 150144;                 // N (fallback) -> 200192
    int* row_ptr = ws + 200192;                 // N+1 (fallback) -> 250240
    int* pos     = ws + 250240;                 // N (fallback) -> 300288
    int* blk_sum = ws + 300288;                 // 64
    int* gcur    = ws + 300352;                 // 256 -> 300608, pad 300672
    uint_t* csr  = (uint_t*)(ws + 300672);      // nb*CSR_CAP entries
    size_t stag_off = 300672 + (size_t)nb * CSR_CAP;
    stag_off = (stag_off + 1) & ~(size_t)1;
    uint2* staging = (uint2*)(ws + stag_off);   // nb*BKT_CAP uint2
    size_t xb_off = (stag_off + 2 * (size_t)nb * BKT_CAP + 3) & ~(size_t)3;
    uint4* xb = (uint4*)(ws + xb_off);          // TERM4 (16B aligned)

    const size_t needA = (xb_off + (size_t)M_TERMS * TERM4 * 4) * 4;
    const int pathA = (ws_size >= needA);

    if (pathA) {
        init_kernel<<<1, 256, 0, stream>>>(gcur);
        binA_cvt_kernel<<<nblkA + ncvt, 256, 0, stream>>>(esrc, edst, ew, gcur,
                                                          staging, E, nblkA,
                                                          (const float4*)x, xb, NC / 8);
        binB_kernel<<<nb, 256, 0, stream>>>(staging, gcur, rp, perm, csr, N);
    } else {
        // fallback: cvt-only fused kernel (nblkA = 0), then hist/scan/scatter
        binA_cvt_kernel<<<ncvt, 256, 0, stream>>>(esrc, edst, ew, gcur,
                                                  staging, E, 0,
                                                  (const float4*)x, xb, NC / 8);
        hipMemsetAsync(cnt, 0, (size_t)N * sizeof(int), stream);
        hist_kernel<<<(E + 255) / 256, 256, 0, stream>>>(esrc, cnt, E);
        const int nsb = (N + 1023) / 1024;
        scan1_kernel<<<nsb, 1024, 0, stream>>>(cnt, row_ptr, blk_sum, N);
        scan3_kernel<<<(N + 255) / 256, 256, 0, stream>>>(row_ptr, pos, rp, perm,
                                                          blk_sum, cnt, N, nsb);
        hipMemsetAsync(csr, 0, (size_t)nb * CSR_CAP * sizeof(uint_t), stream);
        scatter_kernel<<<(E + 255) / 256, 256, 0, stream>>>(esrc, edst, ew, pos, csr, E);
    }

    const int tgrid = (N * 8 + 255) / 256;   // 8 lanes per row

    if (pathA) {
        uint4* terms = xb + TERM4;  // M_TERMS-1 consecutive buffers
        taylor_kernel<<<tgrid, 256, 0, stream>>>(rp, perm, csr, xb, terms, nullptr,
                                                 nullptr, nullptr, 0, tp, 1.0f, N, 0);
        for (int k = 2; k <= M_TERMS - 1; ++k) {
            taylor_kernel<<<tgrid, 256, 0, stream>>>(rp, perm, csr,
                                                     terms + (size_t)(k - 2) * TERM4,
                                                     terms + (size_t)(k - 1) * TERM4,
                                                     nullptr, nullptr, nullptr, 0,
                                                     tp, 1.0f / (float)k, N, 0);
        }
        taylor_kernel<<<tgrid, 256, 0, stream>>>(rp, perm, csr,
                                                 terms + (size_t)(M_TERMS - 2) * TERM4,
                                                 terms, (float4*)out, (const float4*)x,
                                                 terms, TERM4,
                                                 tp, 1.0f / (float)M_TERMS, N, 3);
    } else {
        uint4* term_a = xb + TERM4;
        uint4* term_b = term_a + TERM4;
        taylor_kernel<<<tgrid, 256, 0, stream>>>(rp, perm, csr, xb, term_b,
                                                 (float4*)out, (const float4*)x,
                                                 nullptr, 0, tp, 1.0f, N, 1);
        const uint4* tin = term_b;
        uint4* tout = term_a;
        for (int k = 2; k <= M_TERMS; ++k) {
            taylor_kernel<<<tgrid, 256, 0, stream>>>(rp, perm, csr, tin, tout,
                                                     (float4*)out, (const float4*)x,
                                                     nullptr, 0, tp,
                                                     1.0f / (float)k, N, 2);
            const uint4* tmp = tin;
            tin = tout;
            tout = (uint4*)tmp;
        }
    }
}